// Round 1
// baseline (141.293 us; speedup 1.0000x reference)
//
#include <hip/hip_runtime.h>
#include <math.h>

// GaussianRBF: y[b,s,o] = exp(-||(x[b,s]-mu[o])/sigma[o]||^2), normalized over o.
// B=8,S=4096 -> 32768 points; O=1024; D=3. Output 134 MB f32 -> write-BW bound.
//
// One wave per point: lane l owns outputs o = j*256 + l*4 + c (j=0..3,c=0..3)
// -> each float4 store is a fully coalesced 1 KB wave-write.
// Per-lane register constants (mu x3 + inv_sigma^2, 16 outputs) loaded once,
// amortized over the grid-stride point loop. Normalization sum via shfl_xor.

#define O_DIM 1024
#define NPOINTS (8 * 4096)
#define BLOCKS 1024   // 4096 waves total -> 8 points per wave

__global__ __launch_bounds__(256, 4)
void GaussianRBF_83330955477629_kernel(const float* __restrict__ x,
                                       const float* __restrict__ mus,
                                       const float* __restrict__ log_sigmas,
                                       float* __restrict__ y) {
    const int lane  = threadIdx.x & 63;
    const int wave  = blockIdx.x * (blockDim.x >> 6) + (threadIdx.x >> 6);
    const int nwav  = gridDim.x * (blockDim.x >> 6);

    // ---- per-lane constants for its 16 outputs ----
    float mu0[16], mu1[16], mu2[16], w[16];   // w = 1/sigma^2 = exp(-2*log_sigma)
#pragma unroll
    for (int j = 0; j < 4; ++j) {
        const int o = j * 256 + lane * 4;          // 4 consecutive outputs
        // mus[3o .. 3o+11] : 48 bytes, 16B-aligned (48*lane)
        const float4 m0 = *(const float4*)(mus + 3 * o);
        const float4 m1 = *(const float4*)(mus + 3 * o + 4);
        const float4 m2 = *(const float4*)(mus + 3 * o + 8);
        mu0[j*4+0] = m0.x; mu1[j*4+0] = m0.y; mu2[j*4+0] = m0.z;
        mu0[j*4+1] = m0.w; mu1[j*4+1] = m1.x; mu2[j*4+1] = m1.y;
        mu0[j*4+2] = m1.z; mu1[j*4+2] = m1.w; mu2[j*4+2] = m2.x;
        mu0[j*4+3] = m2.y; mu1[j*4+3] = m2.z; mu2[j*4+3] = m2.w;
        const float4 ls = *(const float4*)(log_sigmas + o);
        w[j*4+0] = __expf(-2.0f * ls.x);
        w[j*4+1] = __expf(-2.0f * ls.y);
        w[j*4+2] = __expf(-2.0f * ls.z);
        w[j*4+3] = __expf(-2.0f * ls.w);
    }

    // ---- grid-stride over points; one wave handles a full point ----
    for (int p = wave; p < NPOINTS; p += nwav) {
        const float x0 = x[p * 3 + 0];
        const float x1 = x[p * 3 + 1];
        const float x2 = x[p * 3 + 2];

        float yv[16];
        float s = 0.0f;
#pragma unroll
        for (int k = 0; k < 16; ++k) {
            const float d0 = x0 - mu0[k];
            const float d1 = x1 - mu1[k];
            const float d2 = x2 - mu2[k];
            const float q  = d0 * d0 + d1 * d1 + d2 * d2;
            const float v  = __expf(-w[k] * q);
            yv[k] = v;
            s += v;
        }
        // wave-wide sum (64 lanes)
#pragma unroll
        for (int off = 32; off; off >>= 1) s += __shfl_xor(s, off, 64);
        const float r = 1.0f / s;

        float* yp = y + (size_t)p * O_DIM;
#pragma unroll
        for (int j = 0; j < 4; ++j) {
            float4 out;
            out.x = yv[j*4+0] * r;
            out.y = yv[j*4+1] * r;
            out.z = yv[j*4+2] * r;
            out.w = yv[j*4+3] * r;
            *(float4*)(yp + j * 256 + lane * 4) = out;  // coalesced 1 KB/wave
        }
    }
}

extern "C" void kernel_launch(void* const* d_in, const int* in_sizes, int n_in,
                              void* d_out, int out_size, void* d_ws, size_t ws_size,
                              hipStream_t stream) {
    const float* x  = (const float*)d_in[0];
    const float* mu = (const float*)d_in[1];
    const float* ls = (const float*)d_in[2];
    float* y = (float*)d_out;
    GaussianRBF_83330955477629_kernel<<<BLOCKS, 256, 0, stream>>>(x, mu, ls, y);
}